// Round 8
// baseline (359.226 us; speedup 1.0000x reference)
//
#include <hip/hip_runtime.h>

#define SPHN 9
#define CHN 64

// ---------------------------------------------------------------------------
// Setup: parallel Wigner-J build (l=1 -> Jout[0..8], l=2 -> Jout[9..33]) in
// double precision (exact reference transcription), PLUS zeroing of counts[N].
// ---------------------------------------------------------------------------
__device__ __forceinline__ void centry(int l, int r, int c, double& re, double& im)
{
    const double is2 = 0.70710678118654752440;
    re = 0.0; im = 0.0;
    int m = r - l;
    if (m == 0) {
        if (c == l) re = 1.0;
    } else if (m > 0) {
        if (c == l - m) re = is2;
        else if (c == l + m) re = (m & 1) ? -is2 : is2;
    } else {
        if (c == l + m) im = is2;
        else if (c == l - m) im = (m & 1) ? is2 : -is2;
    }
}

__global__ __launch_bounds__(256) void k_setup(float* __restrict__ Jout,
                                               int* __restrict__ counts, int N)
{
    int gid = blockIdx.x * 256 + threadIdx.x;
    if (counts != nullptr && gid < N) counts[gid] = 0;
    if (blockIdx.x != 0) return;

    const int tid = threadIdx.x;
    __shared__ double factS[9];
    __shared__ double dS[34];
    if (tid < 9) {
        double f = 1.0;
        for (int q = 2; q <= tid; ++q) f *= (double)q;
        factS[tid] = f;
    }
    __syncthreads();

    int l = 0, i = 0, j = 0, base = 0, n = 0;
    bool active = false;
    if (tid < 9)       { l = 1; n = 3; base = 0; i = tid / 3;       j = tid % 3;       active = true; }
    else if (tid < 34) { l = 2; n = 5; base = 9; i = (tid - 9) / 5; j = (tid - 9) % 5; active = true; }

    if (active) {
        const double is2 = 0.70710678118654752440;
        int mp = i - l, m = j - l;
        double val = 0.0;
        int k0 = (m - mp) > 0 ? (m - mp) : 0;
        int k1 = (l + m < l - mp) ? (l + m) : (l - mp);
        for (int k = k0; k <= k1; ++k) {
            double sign = ((mp - m + k) & 1) ? -1.0 : 1.0;
            double num = sign * sqrt(factS[l + mp] * factS[l - mp] * factS[l + m] * factS[l - m]);
            double den = factS[l + m - k] * factS[k] * factS[mp - m + k] * factS[l - mp - k];
            double cp = 1.0;
            for (int q = 0; q < 2 * l + m - mp - 2 * k; ++q) cp *= is2;
            double sp = 1.0;
            for (int q = 0; q < mp - m + 2 * k; ++q) sp *= is2;
            val += num / den * cp * sp;
        }
        dS[base + i * n + j] = val;
    }
    __syncthreads();

    if (active) {
        const int n1 = n - 1;
        double jr = 0.0;
        double cjr, cji, ckr, cki;
        {
            int k = i;
            centry(l, j, j, cjr, cji);
            double tr = dS[base + k * n + j] * cjr;
            double ti = -dS[base + k * n + j] * cji;
            if (n1 - j != j) {
                centry(l, j, n1 - j, cjr, cji);
                tr += dS[base + k * n + (n1 - j)] * cjr;
                ti += -dS[base + k * n + (n1 - j)] * cji;
            }
            centry(l, i, i, ckr, cki);
            jr += ckr * tr - cki * ti;
        }
        if (n1 - i != i) {
            int k = n1 - i;
            centry(l, j, j, cjr, cji);
            double tr = dS[base + k * n + j] * cjr;
            double ti = -dS[base + k * n + j] * cji;
            if (n1 - j != j) {
                centry(l, j, n1 - j, cjr, cji);
                tr += dS[base + k * n + (n1 - j)] * cjr;
                ti += -dS[base + k * n + (n1 - j)] * cji;
            }
            centry(l, i, n1 - i, ckr, cki);
            jr += ckr * tr - cki * ti;
        }
        Jout[base + i * n + j] = (float)jr;
    }
}

// ---------------------------------------------------------------------------
// Per-node (4 nodes/block): xm = node_feats @ W_msg1, rows {1,3,4,5,7,8} only.
// ---------------------------------------------------------------------------
__global__ __launch_bounds__(256) void k_xm(const float* __restrict__ nf,
                                            const float* __restrict__ m1,
                                            float* __restrict__ xm6, int N)
{
    const int tid = threadIdx.x;
    const int w = tid >> 6;
    const int t = tid & 63;
    const int n = blockIdx.x * 4 + w;
    __shared__ float sx[4][6 * 64];
    if (n < N) {
        const float* xp = nf + (size_t)n * (SPHN * CHN);
        sx[w][0 * 64 + t] = xp[1 * 64 + t];
        sx[w][1 * 64 + t] = xp[3 * 64 + t];
        sx[w][2 * 64 + t] = xp[4 * 64 + t];
        sx[w][3 * 64 + t] = xp[5 * 64 + t];
        sx[w][4 * 64 + t] = xp[7 * 64 + t];
        sx[w][5 * 64 + t] = xp[8 * 64 + t];
    }
    __syncthreads();
    if (n >= N) return;
    float a0 = 0.f, a1 = 0.f, a2 = 0.f, a3 = 0.f, a4 = 0.f, a5 = 0.f;
    for (int c = 0; c < 64; ++c) {
        float m = m1[c * 64 + t];
        a0 += sx[w][0 * 64 + c] * m;
        a1 += sx[w][1 * 64 + c] * m;
        a2 += sx[w][2 * 64 + c] * m;
        a3 += sx[w][3 * 64 + c] * m;
        a4 += sx[w][4 * 64 + c] * m;
        a5 += sx[w][5 * 64 + c] * m;
    }
    float* op = xm6 + (size_t)n * 384;
    op[0 * 64 + t] = a0;
    op[1 * 64 + t] = a1;
    op[2 * 64 + t] = a2;
    op[3 * 64 + t] = a3;
    op[4 * 64 + t] = a4;
    op[5 * 64 + t] = a5;
}

__device__ __forceinline__ float siluf(float x) { return x / (1.f + expf(-x)); }

// ---------------------------------------------------------------------------
// Histogram of dst
// ---------------------------------------------------------------------------
__global__ __launch_bounds__(256) void k_hist(const int* __restrict__ eidx,
                                              int* __restrict__ counts, int E)
{
    int e = blockIdx.x * 256 + threadIdx.x;
    if (e < E) atomicAdd(&counts[eidx[E + e]], 1);
}

// ---------------------------------------------------------------------------
// Exclusive scan of counts[N] -> offsets/cursors, offsets[N]=total.
// ---------------------------------------------------------------------------
__global__ __launch_bounds__(1024) void k_scan(const int* __restrict__ counts,
                                               int* __restrict__ offsets,
                                               int* __restrict__ cursors, int N)
{
    __shared__ int wsum[16];
    __shared__ int wpre[16];
    const int tid = threadIdx.x;
    const int lane = tid & 63;
    const int wid = tid >> 6;
    const int per = (N + 1023) >> 10;
    const int begin = tid * per;
    const int endi = (begin + per < N) ? (begin + per) : N;

    int s = 0;
    for (int i = begin; i < endi; ++i) s += counts[i];

    int inc = s;
#pragma unroll
    for (int off = 1; off < 64; off <<= 1) {
        int u = __shfl_up(inc, off, 64);
        if (lane >= off) inc += u;
    }
    if (lane == 63) wsum[wid] = inc;
    __syncthreads();
    if (wid == 0) {
        int v = (lane < 16) ? wsum[lane] : 0;
        int winc = v;
#pragma unroll
        for (int off = 1; off < 16; off <<= 1) {
            int u = __shfl_up(winc, off, 64);
            if (lane >= off) winc += u;
        }
        if (lane < 16) wpre[lane] = winc - v;
    }
    __syncthreads();
    int run = wpre[wid] + (inc - s);
    for (int i = begin; i < endi; ++i) {
        int c = counts[i];
        offsets[i] = run;
        cursors[i] = run;
        run += c;
    }
    if (endi == N && begin < N) offsets[N] = run;
}

// ---------------------------------------------------------------------------
// Scatter: perm[pos] = e and srcs[pos] = src(e)  (sorted-by-dst layout)
// ---------------------------------------------------------------------------
__global__ __launch_bounds__(256) void k_scatter(const int* __restrict__ eidx,
                                                 int* __restrict__ cursors,
                                                 int* __restrict__ perm,
                                                 int* __restrict__ srcs, int E)
{
    int e = blockIdx.x * 256 + threadIdx.x;
    if (e < E) {
        int pos = atomicAdd(&cursors[eidx[E + e]], 1);
        perm[pos] = e;
        srcs[pos] = eidx[e];
    }
}

// ---------------------------------------------------------------------------
// Merged per-edge kernel, ONE THREAD PER EDGE in SORTED order:
//   i = sorted index, e = perm[i]
//   - angles from evec[e] (random 12B read)
//   - Wigner Q (20 live coeffs) -> Qe[i]        (coalesced at sorted pos)
//   - radial MLP fully in registers -> radg[i]  (coalesced at sorted pos)
// No LDS phases, no barriers. Weights are wave-uniform -> scalar loads.
// rbf[64] + rad[64] kept in registers with static (fully unrolled) indexing.
// ---------------------------------------------------------------------------
__global__ __launch_bounds__(256) void k_edge_all(const float* __restrict__ evec,
                                                  const int* __restrict__ perm,
                                                  const float* __restrict__ Jc,
                                                  const float* __restrict__ w1,
                                                  const float* __restrict__ b1,
                                                  const float* __restrict__ w2,
                                                  float* __restrict__ Qe,
                                                  float* __restrict__ radg,
                                                  int E)
{
    __shared__ float sJ[34];
    const int tid = threadIdx.x;
    if (tid < 34) sJ[tid] = Jc[tid];
    __syncthreads();

    const int i = blockIdx.x * 256 + tid;
    if (i >= E) return;
    const int e = perm[i];

    float vx = evec[(size_t)e * 3 + 0];
    float vy = evec[(size_t)e * 3 + 1];
    float vz = evec[(size_t)e * 3 + 2];
    float dist = sqrtf(vx * vx + vy * vy + vz * vz);
    float inv = 1.0f / fmaxf(dist, 1e-7f);
    float xn = fminf(fmaxf(vx * inv, -1.f), 1.f);
    float yn = fminf(fmaxf(vy * inv, -1.f), 1.f);
    float zn = fminf(fmaxf(vz * inv, -1.f), 1.f);
    float beta = acosf(fminf(fmaxf(yn, -1.f + 1e-7f), 1.f - 1e-7f));
    float alpha = atan2f(xn, zn);
    const float bA = -beta;
    const float cA = -alpha;

    float* qo = Qe + (size_t)i * 20;

    // ---- Wigner l = 1 ----
    {
        const float* J1 = sJ;
        float cb[3], sb[3], cz[3], sz[3];
#pragma unroll
        for (int k = 0; k < 3; ++k) {
            __sincosf((float)(1 - k) * bA, &sb[k], &cb[k]);
            __sincosf((float)(k - 1) * cA, &sz[k], &cz[k]);
        }
        cb[1] = 0.f; cz[1] = 0.f;
        float A[2][3], Bc[3][2], W[2][2];
#pragma unroll
        for (int a = 0; a < 2; ++a) {
            int r = a * 2;
#pragma unroll
            for (int m = 0; m < 3; ++m)
                A[a][m] = J1[r * 3 + m] * cb[m] + J1[r * 3 + (2 - m)] * sb[2 - m];
        }
#pragma unroll
        for (int m = 0; m < 3; ++m)
#pragma unroll
            for (int b = 0; b < 2; ++b) {
                int c = b * 2;
                Bc[m][b] = J1[m * 3 + c] * cz[c] + J1[m * 3 + (2 - c)] * sz[c];
            }
#pragma unroll
        for (int a = 0; a < 2; ++a)
#pragma unroll
            for (int b = 0; b < 2; ++b) {
                float w = 0.f;
#pragma unroll
                for (int m = 0; m < 3; ++m) w += A[a][m] * Bc[m][b];
                W[a][b] = w;
            }
        float4 q;
        q.x = W[0][0] * W[0][0] + W[1][0] * W[1][0];
        q.y = W[0][0] * W[0][1] + W[1][0] * W[1][1];
        q.z = W[0][1] * W[0][0] + W[1][1] * W[1][0];
        q.w = W[0][1] * W[0][1] + W[1][1] * W[1][1];
        *(float4*)&qo[0] = q;
    }

    // ---- Wigner l = 2 ----
    {
        const float* J2 = sJ + 9;
        float cb[5], sb[5], cz[5], sz[5];
#pragma unroll
        for (int k = 0; k < 5; ++k) {
            __sincosf((float)(2 - k) * bA, &sb[k], &cb[k]);
            __sincosf((float)(k - 2) * cA, &sz[k], &cz[k]);
        }
        cb[2] = 0.f; cz[2] = 0.f;
        const int rmap[4] = {0, 1, 3, 4};
        float A[4][5], Bc[5][4], W[4][4];
#pragma unroll
        for (int a = 0; a < 4; ++a) {
            int r = rmap[a];
#pragma unroll
            for (int m = 0; m < 5; ++m)
                A[a][m] = J2[r * 5 + m] * cb[m] + J2[r * 5 + (4 - m)] * sb[4 - m];
        }
#pragma unroll
        for (int m = 0; m < 5; ++m)
#pragma unroll
            for (int b = 0; b < 4; ++b) {
                int c = rmap[b];
                Bc[m][b] = J2[m * 5 + c] * cz[c] + J2[m * 5 + (4 - c)] * sz[c];
            }
#pragma unroll
        for (int a = 0; a < 4; ++a)
#pragma unroll
            for (int b = 0; b < 4; ++b) {
                float w = 0.f;
#pragma unroll
                for (int m = 0; m < 5; ++m) w += A[a][m] * Bc[m][b];
                W[a][b] = w;
            }
#pragma unroll
        for (int a = 0; a < 4; ++a) {
            float4 q;
            q.x = W[0][a] * W[0][0] + W[1][a] * W[1][0] + W[2][a] * W[2][0] + W[3][a] * W[3][0];
            q.y = W[0][a] * W[0][1] + W[1][a] * W[1][1] + W[2][a] * W[2][1] + W[3][a] * W[3][1];
            q.z = W[0][a] * W[0][2] + W[1][a] * W[1][2] + W[2][a] * W[2][2] + W[3][a] * W[3][2];
            q.w = W[0][a] * W[0][3] + W[1][a] * W[1][3] + W[2][a] * W[2][3] + W[3][a] * W[3][3];
            *(float4*)&qo[4 + a * 4] = q;
        }
    }

    // ---- radial MLP, fully register-resident ----
    float rbf[64];
    const float step = 6.0f / 63.0f;
#pragma unroll
    for (int k = 0; k < 64; ++k) {
        float d = dist - step * (float)k;
        rbf[k] = __expf(-55.125f * d * d);
    }

    float rad[64];
#pragma unroll
    for (int c = 0; c < 64; ++c) rad[c] = 0.f;

#pragma unroll 1
    for (int jt = 0; jt < 8; ++jt) {
        float h[16];
        {
            float4 b0 = *(const float4*)&b1[jt * 16 + 0];
            float4 b4 = *(const float4*)&b1[jt * 16 + 4];
            float4 b8 = *(const float4*)&b1[jt * 16 + 8];
            float4 bc = *(const float4*)&b1[jt * 16 + 12];
            h[0] = b0.x;  h[1] = b0.y;  h[2] = b0.z;  h[3] = b0.w;
            h[4] = b4.x;  h[5] = b4.y;  h[6] = b4.z;  h[7] = b4.w;
            h[8] = b8.x;  h[9] = b8.y;  h[10] = b8.z; h[11] = b8.w;
            h[12] = bc.x; h[13] = bc.y; h[14] = bc.z; h[15] = bc.w;
        }
        const float* w1p = w1 + jt * 16;
#pragma unroll
        for (int k = 0; k < 64; ++k) {
            float4 a0 = *(const float4*)&w1p[k * 128 + 0];
            float4 a4 = *(const float4*)&w1p[k * 128 + 4];
            float4 a8 = *(const float4*)&w1p[k * 128 + 8];
            float4 ac = *(const float4*)&w1p[k * 128 + 12];
            float r = rbf[k];
            h[0] += r * a0.x;  h[1] += r * a0.y;  h[2] += r * a0.z;  h[3] += r * a0.w;
            h[4] += r * a4.x;  h[5] += r * a4.y;  h[6] += r * a4.z;  h[7] += r * a4.w;
            h[8] += r * a8.x;  h[9] += r * a8.y;  h[10] += r * a8.z; h[11] += r * a8.w;
            h[12] += r * ac.x; h[13] += r * ac.y; h[14] += r * ac.z; h[15] += r * ac.w;
        }
        const float* w2p = w2 + (size_t)(jt * 16) * 64;
#pragma unroll
        for (int jj = 0; jj < 16; ++jj) {
            float hs = siluf(h[jj]);
#pragma unroll
            for (int c4 = 0; c4 < 16; ++c4) {
                float4 wv = *(const float4*)&w2p[jj * 64 + c4 * 4];
                rad[c4 * 4 + 0] += hs * wv.x;
                rad[c4 * 4 + 1] += hs * wv.y;
                rad[c4 * 4 + 2] += hs * wv.z;
                rad[c4 * 4 + 3] += hs * wv.w;
            }
        }
    }

    float dd = dist * (1.0f / 6.0f);
    float env = 0.f;
    if (dd < 1.0f) {
        float d2 = dd * dd;
        float d5 = d2 * d2 * dd;
        env = 1.0f - 21.0f * d5 + 35.0f * d5 * dd - 15.0f * d5 * d2;
    }

    float* rp = radg + (size_t)i * 64;
#pragma unroll
    for (int c4 = 0; c4 < 16; ++c4) {
        float4 o;
        o.x = rad[c4 * 4 + 0] * env;
        o.y = rad[c4 * 4 + 1] * env;
        o.z = rad[c4 * 4 + 2] * env;
        o.w = rad[c4 * 4 + 3] * env;
        *(float4*)&rp[c4 * 4] = o;
    }
}

// ---------------------------------------------------------------------------
// Per-dst-node gather: Qe/radg/srcs are SEQUENTIAL (sorted layout); only the
// xm6[src] read is random. Register accumulate + fused M2/RMS/gamma finalize.
// ---------------------------------------------------------------------------
__global__ __launch_bounds__(64) void k_gather_fin(const int* __restrict__ srcs,
                                                   const int* __restrict__ offsets,
                                                   const float* __restrict__ Qe,
                                                   const float* __restrict__ radg,
                                                   const float* __restrict__ xm6,
                                                   const float* __restrict__ m2,
                                                   const float* __restrict__ gam,
                                                   float* __restrict__ out)
{
    const int n = blockIdx.x;
    const int t = threadIdx.x;
    const int start = offsets[n];
    const int end = offsets[n + 1];

    float a1 = 0.f, a3 = 0.f, a4 = 0.f, a5 = 0.f, a7 = 0.f, a8 = 0.f;
    for (int i = start; i < end; ++i) {
        const int src = srcs[i];
        const float* q = Qe + (size_t)i * 20;
        float4 q0 = *(const float4*)&q[0];
        float4 q1 = *(const float4*)&q[4];
        float4 q2 = *(const float4*)&q[8];
        float4 q3 = *(const float4*)&q[12];
        float4 q4 = *(const float4*)&q[16];
        const float rad = radg[(size_t)i * 64 + t];
        const float* xs = xm6 + (size_t)src * 384;
        float x1 = xs[0 * 64 + t];
        float x3 = xs[1 * 64 + t];
        float x4 = xs[2 * 64 + t];
        float x5 = xs[3 * 64 + t];
        float x7 = xs[4 * 64 + t];
        float x8 = xs[5 * 64 + t];
        a1 += rad * (q0.x * x1 + q0.y * x3);
        a3 += rad * (q0.z * x1 + q0.w * x3);
        a4 += rad * (q1.x * x4 + q1.y * x5 + q1.z * x7 + q1.w * x8);
        a5 += rad * (q2.x * x4 + q2.y * x5 + q2.z * x7 + q2.w * x8);
        a7 += rad * (q3.x * x4 + q3.y * x5 + q3.z * x7 + q3.w * x8);
        a8 += rad * (q4.x * x4 + q4.y * x5 + q4.z * x7 + q4.w * x8);
    }

    __shared__ float sa[6 * 64];
    sa[0 * 64 + t] = a1;
    sa[1 * 64 + t] = a3;
    sa[2 * 64 + t] = a4;
    sa[3 * 64 + t] = a5;
    sa[4 * 64 + t] = a7;
    sa[5 * 64 + t] = a8;
    __syncthreads();
    float v0 = 0.f, v1 = 0.f, v2 = 0.f, v3 = 0.f, v4 = 0.f, v5 = 0.f;
    for (int c = 0; c < 64; ++c) {
        float m = m2[c * 64 + t];
        v0 += sa[0 * 64 + c] * m;
        v1 += sa[1 * 64 + c] * m;
        v2 += sa[2 * 64 + c] * m;
        v3 += sa[3 * 64 + c] * m;
        v4 += sa[4 * 64 + c] * m;
        v5 += sa[5 * 64 + c] * m;
    }
    float ss = v0 * v0 + v1 * v1 + v2 * v2 + v3 * v3 + v4 * v4 + v5 * v5;
    float rms = sqrtf(ss * (1.0f / 9.0f) + 1e-7f);
    float sc = gam[t] / rms;
    float* op = out + (size_t)n * 576;
    op[0 * 64 + t] = 0.f;
    op[2 * 64 + t] = 0.f;
    op[6 * 64 + t] = 0.f;
    op[1 * 64 + t] = v0 * sc;
    op[3 * 64 + t] = v1 * sc;
    op[4 * 64 + t] = v2 * sc;
    op[5 * 64 + t] = v3 * sc;
    op[7 * 64 + t] = v4 * sc;
    op[8 * 64 + t] = v5 * sc;
}

// ---------------------------------------------------------------------------
// Legacy fallback path (small ws): LDS-phased k_rad + atomic scatter + finalize
// ---------------------------------------------------------------------------
__global__ __launch_bounds__(256, 4) void k_rad_lds(const float* __restrict__ evec,
                                                    const float* __restrict__ w1,
                                                    const float* __restrict__ b1,
                                                    const float* __restrict__ w2,
                                                    float* __restrict__ radg,
                                                    int E)
{
    __shared__ float rbfT[64 * 64];
    __shared__ float hT[32 * 64];
    __shared__ float distS[64];
    __shared__ float envS[64];
    const int tid = threadIdx.x;
    const int base = blockIdx.x * 64;

    if (tid < 64) {
        int e = base + tid;
        float dist = 0.f;
        if (e < E) {
            float vx = evec[(size_t)e * 3 + 0];
            float vy = evec[(size_t)e * 3 + 1];
            float vz = evec[(size_t)e * 3 + 2];
            dist = sqrtf(vx * vx + vy * vy + vz * vz);
        }
        distS[tid] = dist;
        float dd = dist * (1.0f / 6.0f);
        float env = 0.f;
        if (dd < 1.0f) {
            float d2 = dd * dd;
            float d5 = d2 * d2 * dd;
            env = 1.0f - 21.0f * d5 + 35.0f * d5 * dd - 15.0f * d5 * d2;
        }
        envS[tid] = env;
    }
    __syncthreads();

    const float step = 6.0f / 63.0f;
#pragma unroll
    for (int p = 0; p < 16; ++p) {
        int idx = p * 256 + tid;
        int k = idx >> 6, e2 = idx & 63;
        float diff = distS[e2] - step * (float)k;
        rbfT[idx] = __expf(-55.125f * diff * diff);
    }

    const int egB = tid & 15;
    const int jgB = tid >> 4;
    const int egC = tid >> 4;
    const int tgC = tid & 15;

    float acc[4][4];
#pragma unroll
    for (int ee = 0; ee < 4; ++ee)
#pragma unroll
        for (int cc = 0; cc < 4; ++cc) acc[ee][cc] = 0.f;

    for (int q = 0; q < 4; ++q) {
        float h00, h01, h10, h11, h20, h21, h30, h31;
        {
            const float2 bb = *(const float2*)&b1[q * 32 + jgB * 2];
            h00 = bb.x; h01 = bb.y; h10 = bb.x; h11 = bb.y;
            h20 = bb.x; h21 = bb.y; h30 = bb.x; h31 = bb.y;
            const float* w1p = w1 + q * 32 + jgB * 2;
#pragma unroll 4
            for (int k = 0; k < 64; ++k) {
                float2 wv = *(const float2*)&w1p[k * 128];
                float4 rb = *(const float4*)&rbfT[k * 64 + egB * 4];
                h00 += rb.x * wv.x; h01 += rb.x * wv.y;
                h10 += rb.y * wv.x; h11 += rb.y * wv.y;
                h20 += rb.z * wv.x; h21 += rb.z * wv.y;
                h30 += rb.w * wv.x; h31 += rb.w * wv.y;
            }
        }
        __syncthreads();
        {
            float4 v0, v1;
            v0.x = siluf(h00); v0.y = siluf(h10); v0.z = siluf(h20); v0.w = siluf(h30);
            v1.x = siluf(h01); v1.y = siluf(h11); v1.z = siluf(h21); v1.w = siluf(h31);
            *(float4*)&hT[(jgB * 2 + 0) * 64 + egB * 4] = v0;
            *(float4*)&hT[(jgB * 2 + 1) * 64 + egB * 4] = v1;
        }
        __syncthreads();

        const float* w2p = w2 + (size_t)(q * 32) * 64 + tgC * 4;
#pragma unroll 4
        for (int j2 = 0; j2 < 32; ++j2) {
            float4 wv = *(const float4*)&w2p[j2 * 64];
            float4 hv = *(const float4*)&hT[j2 * 64 + egC * 4];
            acc[0][0] += hv.x * wv.x; acc[0][1] += hv.x * wv.y;
            acc[0][2] += hv.x * wv.z; acc[0][3] += hv.x * wv.w;
            acc[1][0] += hv.y * wv.x; acc[1][1] += hv.y * wv.y;
            acc[1][2] += hv.y * wv.z; acc[1][3] += hv.y * wv.w;
            acc[2][0] += hv.z * wv.x; acc[2][1] += hv.z * wv.y;
            acc[2][2] += hv.z * wv.z; acc[2][3] += hv.z * wv.w;
            acc[3][0] += hv.w * wv.x; acc[3][1] += hv.w * wv.y;
            acc[3][2] += hv.w * wv.z; acc[3][3] += hv.w * wv.w;
        }
    }

#pragma unroll
    for (int ee = 0; ee < 4; ++ee) {
        int e = base + egC * 4 + ee;
        if (e < E) {
            float envv = envS[egC * 4 + ee];
            float4 o;
            o.x = acc[ee][0] * envv;
            o.y = acc[ee][1] * envv;
            o.z = acc[ee][2] * envv;
            o.w = acc[ee][3] * envv;
            *(float4*)&radg[(size_t)e * 64 + tgC * 4] = o;
        }
    }
}

__device__ __forceinline__ float wig_entry(int l, int i, int j, float bA, float cA,
                                           const float* __restrict__ J, int n)
{
    if (i == l) return 0.f;
    const int j2 = 2 * l - j;
    float Pij = 0.f, Pij2 = 0.f;
    for (int k = 0; k < n; ++k) {
        float sbk, cbk;
        __sincosf((float)(l - k) * bA, &sbk, &cbk);
        if (k == l) cbk = 0.f;
        float zj  = cbk * J[k * n + j]  + sbk * J[(2 * l - k) * n + j];
        float zj2 = cbk * J[k * n + j2] + sbk * J[(2 * l - k) * n + j2];
        Pij  += J[i * n + k] * zj;
        Pij2 += J[i * n + k] * zj2;
    }
    float s_, c_;
    __sincosf((float)(l - j) * cA, &s_, &c_);
    float czj = (j == l) ? 0.f : c_;
    float szj = -s_;
    return Pij * czj + Pij2 * szj;
}

__global__ __launch_bounds__(64) void k_edge2(const float* __restrict__ evec,
                                              const int* __restrict__ eidx,
                                              const float* __restrict__ radg,
                                              const float* __restrict__ Jc,
                                              const float* __restrict__ xm6,
                                              float* __restrict__ acc, int E)
{
    const int e = blockIdx.x;
    const int t = threadIdx.x;
    __shared__ float s_W1[9], s_W2[25], s_Q1[9], s_Q2[25];

    float vx = evec[(size_t)e * 3 + 0];
    float vy = evec[(size_t)e * 3 + 1];
    float vz = evec[(size_t)e * 3 + 2];
    float dist = sqrtf(vx * vx + vy * vy + vz * vz);
    float inv = 1.0f / fmaxf(dist, 1e-7f);
    float xn = fminf(fmaxf(vx * inv, -1.f), 1.f);
    float yn = fminf(fmaxf(vy * inv, -1.f), 1.f);
    float zn = fminf(fmaxf(vz * inv, -1.f), 1.f);
    float beta = acosf(fminf(fmaxf(yn, -1.f + 1e-7f), 1.f - 1e-7f));
    float alpha = atan2f(xn, zn);
    float bA = -beta;
    float cA = -alpha;

    if (t < 25) {
        s_W2[t] = wig_entry(2, t / 5, t % 5, bA, cA, Jc + 9, 5);
    } else if (t >= 32 && t < 41) {
        int u = t - 32;
        s_W1[u] = wig_entry(1, u / 3, u % 3, bA, cA, Jc, 3);
    }
    __syncthreads();

    if (t < 25) {
        int i = t / 5, j = t % 5;
        float qv = 0.f;
#pragma unroll
        for (int k = 0; k < 5; ++k) qv += s_W2[k * 5 + i] * s_W2[k * 5 + j];
        s_Q2[t] = qv;
    } else if (t >= 32 && t < 41) {
        int u = t - 32;
        int i = u / 3, j = u % 3;
        float qv = 0.f;
#pragma unroll
        for (int k = 0; k < 3; ++k) qv += s_W1[k * 3 + i] * s_W1[k * 3 + j];
        s_Q1[u] = qv;
    }
    __syncthreads();

    const float rad = radg[(size_t)e * 64 + t];
    const int src = eidx[e];
    const int dst = eidx[E + e];
    const float* xs = xm6 + (size_t)src * 384;
    float x1 = xs[0 * 64 + t];
    float x3 = xs[1 * 64 + t];
    float x4 = xs[2 * 64 + t];
    float x5 = xs[3 * 64 + t];
    float x7 = xs[4 * 64 + t];
    float x8 = xs[5 * 64 + t];

    float m1v = rad * (s_Q1[0] * x1 + s_Q1[2] * x3);
    float m3v = rad * (s_Q1[6] * x1 + s_Q1[8] * x3);
    float m4v = rad * (s_Q2[0]  * x4 + s_Q2[1]  * x5 + s_Q2[3]  * x7 + s_Q2[4]  * x8);
    float m5v = rad * (s_Q2[5]  * x4 + s_Q2[6]  * x5 + s_Q2[8]  * x7 + s_Q2[9]  * x8);
    float m7v = rad * (s_Q2[15] * x4 + s_Q2[16] * x5 + s_Q2[18] * x7 + s_Q2[19] * x8);
    float m8v = rad * (s_Q2[20] * x4 + s_Q2[21] * x5 + s_Q2[23] * x7 + s_Q2[24] * x8);

    float* ad = acc + (size_t)dst * 576;
    atomicAdd(ad + 1 * 64 + t, m1v);
    atomicAdd(ad + 3 * 64 + t, m3v);
    atomicAdd(ad + 4 * 64 + t, m4v);
    atomicAdd(ad + 5 * 64 + t, m5v);
    atomicAdd(ad + 7 * 64 + t, m7v);
    atomicAdd(ad + 8 * 64 + t, m8v);
}

__global__ __launch_bounds__(64) void k_fin(const float* __restrict__ m2,
                                            const float* __restrict__ gam,
                                            float* __restrict__ out)
{
    const int n = blockIdx.x;
    const int t = threadIdx.x;
    __shared__ float sa[6 * 64];
    float* op = out + (size_t)n * 576;
    sa[0 * 64 + t] = op[1 * 64 + t];
    sa[1 * 64 + t] = op[3 * 64 + t];
    sa[2 * 64 + t] = op[4 * 64 + t];
    sa[3 * 64 + t] = op[5 * 64 + t];
    sa[4 * 64 + t] = op[7 * 64 + t];
    sa[5 * 64 + t] = op[8 * 64 + t];
    __syncthreads();
    float v0 = 0.f, v1 = 0.f, v2 = 0.f, v3 = 0.f, v4 = 0.f, v5 = 0.f;
    for (int c = 0; c < 64; ++c) {
        float m = m2[c * 64 + t];
        v0 += sa[0 * 64 + c] * m;
        v1 += sa[1 * 64 + c] * m;
        v2 += sa[2 * 64 + c] * m;
        v3 += sa[3 * 64 + c] * m;
        v4 += sa[4 * 64 + c] * m;
        v5 += sa[5 * 64 + c] * m;
    }
    float ss = v0 * v0 + v1 * v1 + v2 * v2 + v3 * v3 + v4 * v4 + v5 * v5;
    float rms = sqrtf(ss * (1.0f / 9.0f) + 1e-7f);
    float sc = gam[t] / rms;
    op[0 * 64 + t] = 0.f;
    op[2 * 64 + t] = 0.f;
    op[6 * 64 + t] = 0.f;
    op[1 * 64 + t] = v0 * sc;
    op[3 * 64 + t] = v1 * sc;
    op[4 * 64 + t] = v2 * sc;
    op[5 * 64 + t] = v3 * sc;
    op[7 * 64 + t] = v4 * sc;
    op[8 * 64 + t] = v5 * sc;
}

static inline size_t align256(size_t x) { return (x + 255) & ~(size_t)255; }

extern "C" void kernel_launch(void* const* d_in, const int* in_sizes, int n_in,
                              void* d_out, int out_size, void* d_ws, size_t ws_size,
                              hipStream_t stream)
{
    const float* nf  = (const float*)d_in[0];
    const float* ev  = (const float*)d_in[1];
    const int*   ei  = (const int*)d_in[2];
    const float* w1  = (const float*)d_in[3];
    const float* b1  = (const float*)d_in[4];
    const float* w2  = (const float*)d_in[5];
    const float* m1  = (const float*)d_in[6];
    const float* m2  = (const float*)d_in[7];
    const float* gam = (const float*)d_in[8];

    const int N = in_sizes[0] / (SPHN * CHN);
    const int E = in_sizes[1] / 3;

    float* out = (float*)d_out;
    char* base = (char*)d_ws;
    size_t off = 0;
    float* Jc = (float*)(base + off);            off += align256(34 * sizeof(float));
    float* xm6 = (float*)(base + off);           off += align256((size_t)N * 384 * sizeof(float));
    float* radg = (float*)(base + off);          off += align256((size_t)E * 64 * sizeof(float));
    size_t need_old = off;                       // through radg
    float* Qe = (float*)(base + off);            off += align256((size_t)E * 20 * sizeof(float));
    int* counts = (int*)(base + off);            off += align256((size_t)N * sizeof(int));
    int* offsets = (int*)(base + off);           off += align256((size_t)(N + 1) * sizeof(int));
    int* cursors = (int*)(base + off);           off += align256((size_t)N * sizeof(int));
    int* perm = (int*)(base + off);              off += align256((size_t)E * sizeof(int));
    int* srcs = (int*)(base + off);              off += align256((size_t)E * sizeof(int));
    size_t need_new = off;

    if (ws_size >= need_new) {
        hipLaunchKernelGGL(k_setup, dim3((N + 255) / 256), dim3(256), 0, stream,
                           Jc, counts, N);
        hipLaunchKernelGGL(k_hist, dim3((E + 255) / 256), dim3(256), 0, stream,
                           ei, counts, E);
        hipLaunchKernelGGL(k_scan, dim3(1), dim3(1024), 0, stream,
                           counts, offsets, cursors, N);
        hipLaunchKernelGGL(k_scatter, dim3((E + 255) / 256), dim3(256), 0, stream,
                           ei, cursors, perm, srcs, E);
        hipLaunchKernelGGL(k_xm, dim3((N + 3) / 4), dim3(256), 0, stream,
                           nf, m1, xm6, N);
        hipLaunchKernelGGL(k_edge_all, dim3((E + 255) / 256), dim3(256), 0, stream,
                           ev, perm, Jc, w1, b1, w2, Qe, radg, E);
        hipLaunchKernelGGL(k_gather_fin, dim3(N), dim3(64), 0, stream,
                           srcs, offsets, Qe, radg, xm6, m2, gam, out);
    } else if (ws_size >= need_old) {
        hipLaunchKernelGGL(k_setup, dim3(1), dim3(256), 0, stream,
                           Jc, (int*)nullptr, 0);
        hipLaunchKernelGGL(k_xm, dim3((N + 3) / 4), dim3(256), 0, stream,
                           nf, m1, xm6, N);
        hipMemsetAsync(d_out, 0, (size_t)out_size * sizeof(float), stream);
        hipLaunchKernelGGL(k_rad_lds, dim3((E + 63) / 64), dim3(256), 0, stream,
                           ev, w1, b1, w2, radg, E);
        hipLaunchKernelGGL(k_edge2, dim3(E), dim3(64), 0, stream,
                           ev, ei, radg, Jc, xm6, out, E);
        hipLaunchKernelGGL(k_fin, dim3(N), dim3(64), 0, stream, m2, gam, out);
    }
}

// Round 9
// 187.598 us; speedup vs baseline: 1.9149x; 1.9149x over previous
//
#include <hip/hip_runtime.h>

#define SPHN 9
#define CHN 64
#define TABLE_N 8193              // samples on [0,6], dt = 6/8192
#define TABLE_DT (6.0f / 8192.0f)
#define TABLE_INV_DT (8192.0f / 6.0f)

// ---------------------------------------------------------------------------
// Setup: parallel Wigner-J build (l=1 -> Jout[0..8], l=2 -> Jout[9..33]) in
// double precision (exact reference transcription), PLUS zeroing of counts[N].
// ---------------------------------------------------------------------------
__device__ __forceinline__ void centry(int l, int r, int c, double& re, double& im)
{
    const double is2 = 0.70710678118654752440;
    re = 0.0; im = 0.0;
    int m = r - l;
    if (m == 0) {
        if (c == l) re = 1.0;
    } else if (m > 0) {
        if (c == l - m) re = is2;
        else if (c == l + m) re = (m & 1) ? -is2 : is2;
    } else {
        if (c == l + m) im = is2;
        else if (c == l - m) im = (m & 1) ? is2 : -is2;
    }
}

__global__ __launch_bounds__(256) void k_setup(float* __restrict__ Jout,
                                               int* __restrict__ counts, int N)
{
    int gid = blockIdx.x * 256 + threadIdx.x;
    if (counts != nullptr && gid < N) counts[gid] = 0;
    if (blockIdx.x != 0) return;

    const int tid = threadIdx.x;
    __shared__ double factS[9];
    __shared__ double dS[34];
    if (tid < 9) {
        double f = 1.0;
        for (int q = 2; q <= tid; ++q) f *= (double)q;
        factS[tid] = f;
    }
    __syncthreads();

    int l = 0, i = 0, j = 0, base = 0, n = 0;
    bool active = false;
    if (tid < 9)       { l = 1; n = 3; base = 0; i = tid / 3;       j = tid % 3;       active = true; }
    else if (tid < 34) { l = 2; n = 5; base = 9; i = (tid - 9) / 5; j = (tid - 9) % 5; active = true; }

    if (active) {
        const double is2 = 0.70710678118654752440;
        int mp = i - l, m = j - l;
        double val = 0.0;
        int k0 = (m - mp) > 0 ? (m - mp) : 0;
        int k1 = (l + m < l - mp) ? (l + m) : (l - mp);
        for (int k = k0; k <= k1; ++k) {
            double sign = ((mp - m + k) & 1) ? -1.0 : 1.0;
            double num = sign * sqrt(factS[l + mp] * factS[l - mp] * factS[l + m] * factS[l - m]);
            double den = factS[l + m - k] * factS[k] * factS[mp - m + k] * factS[l - mp - k];
            double cp = 1.0;
            for (int q = 0; q < 2 * l + m - mp - 2 * k; ++q) cp *= is2;
            double sp = 1.0;
            for (int q = 0; q < mp - m + 2 * k; ++q) sp *= is2;
            val += num / den * cp * sp;
        }
        dS[base + i * n + j] = val;
    }
    __syncthreads();

    if (active) {
        const int n1 = n - 1;
        double jr = 0.0;
        double cjr, cji, ckr, cki;
        {
            int k = i;
            centry(l, j, j, cjr, cji);
            double tr = dS[base + k * n + j] * cjr;
            double ti = -dS[base + k * n + j] * cji;
            if (n1 - j != j) {
                centry(l, j, n1 - j, cjr, cji);
                tr += dS[base + k * n + (n1 - j)] * cjr;
                ti += -dS[base + k * n + (n1 - j)] * cji;
            }
            centry(l, i, i, ckr, cki);
            jr += ckr * tr - cki * ti;
        }
        if (n1 - i != i) {
            int k = n1 - i;
            centry(l, j, j, cjr, cji);
            double tr = dS[base + k * n + j] * cjr;
            double ti = -dS[base + k * n + j] * cji;
            if (n1 - j != j) {
                centry(l, j, n1 - j, cjr, cji);
                tr += dS[base + k * n + (n1 - j)] * cjr;
                ti += -dS[base + k * n + (n1 - j)] * cji;
            }
            centry(l, i, n1 - i, ckr, cki);
            jr += ckr * tr - cki * ti;
        }
        Jout[base + i * n + j] = (float)jr;
    }
}

// ---------------------------------------------------------------------------
// Per-node (4 nodes/block): xm = node_feats @ W_msg1, rows {1,3,4,5,7,8} only.
// ---------------------------------------------------------------------------
__global__ __launch_bounds__(256) void k_xm(const float* __restrict__ nf,
                                            const float* __restrict__ m1,
                                            float* __restrict__ xm6, int N)
{
    const int tid = threadIdx.x;
    const int w = tid >> 6;
    const int t = tid & 63;
    const int n = blockIdx.x * 4 + w;
    __shared__ float sx[4][6 * 64];
    if (n < N) {
        const float* xp = nf + (size_t)n * (SPHN * CHN);
        sx[w][0 * 64 + t] = xp[1 * 64 + t];
        sx[w][1 * 64 + t] = xp[3 * 64 + t];
        sx[w][2 * 64 + t] = xp[4 * 64 + t];
        sx[w][3 * 64 + t] = xp[5 * 64 + t];
        sx[w][4 * 64 + t] = xp[7 * 64 + t];
        sx[w][5 * 64 + t] = xp[8 * 64 + t];
    }
    __syncthreads();
    if (n >= N) return;
    float a0 = 0.f, a1 = 0.f, a2 = 0.f, a3 = 0.f, a4 = 0.f, a5 = 0.f;
    for (int c = 0; c < 64; ++c) {
        float m = m1[c * 64 + t];
        a0 += sx[w][0 * 64 + c] * m;
        a1 += sx[w][1 * 64 + c] * m;
        a2 += sx[w][2 * 64 + c] * m;
        a3 += sx[w][3 * 64 + c] * m;
        a4 += sx[w][4 * 64 + c] * m;
        a5 += sx[w][5 * 64 + c] * m;
    }
    float* op = xm6 + (size_t)n * 384;
    op[0 * 64 + t] = a0;
    op[1 * 64 + t] = a1;
    op[2 * 64 + t] = a2;
    op[3 * 64 + t] = a3;
    op[4 * 64 + t] = a4;
    op[5 * 64 + t] = a5;
}

__device__ __forceinline__ float siluf(float x) { return x / (1.f + expf(-x)); }

// ---------------------------------------------------------------------------
// Histogram of dst
// ---------------------------------------------------------------------------
__global__ __launch_bounds__(256) void k_hist(const int* __restrict__ eidx,
                                              int* __restrict__ counts, int E)
{
    int e = blockIdx.x * 256 + threadIdx.x;
    if (e < E) atomicAdd(&counts[eidx[E + e]], 1);
}

// ---------------------------------------------------------------------------
// Exclusive scan of counts[N] -> offsets/cursors, offsets[N]=total.
// ---------------------------------------------------------------------------
__global__ __launch_bounds__(1024) void k_scan(const int* __restrict__ counts,
                                               int* __restrict__ offsets,
                                               int* __restrict__ cursors, int N)
{
    __shared__ int wsum[16];
    __shared__ int wpre[16];
    const int tid = threadIdx.x;
    const int lane = tid & 63;
    const int wid = tid >> 6;
    const int per = (N + 1023) >> 10;
    const int begin = tid * per;
    const int endi = (begin + per < N) ? (begin + per) : N;

    int s = 0;
    for (int i = begin; i < endi; ++i) s += counts[i];

    int inc = s;
#pragma unroll
    for (int off = 1; off < 64; off <<= 1) {
        int u = __shfl_up(inc, off, 64);
        if (lane >= off) inc += u;
    }
    if (lane == 63) wsum[wid] = inc;
    __syncthreads();
    if (wid == 0) {
        int v = (lane < 16) ? wsum[lane] : 0;
        int winc = v;
#pragma unroll
        for (int off = 1; off < 16; off <<= 1) {
            int u = __shfl_up(winc, off, 64);
            if (lane >= off) winc += u;
        }
        if (lane < 16) wpre[lane] = winc - v;
    }
    __syncthreads();
    int run = wpre[wid] + (inc - s);
    for (int i = begin; i < endi; ++i) {
        int c = counts[i];
        offsets[i] = run;
        cursors[i] = run;
        run += c;
    }
    if (endi == N && begin < N) offsets[N] = run;
}

// ---------------------------------------------------------------------------
// Scatter: perm[pos] = e and srcs[pos] = src(e)  (sorted-by-dst layout)
// ---------------------------------------------------------------------------
__global__ __launch_bounds__(256) void k_scatter(const int* __restrict__ eidx,
                                                 int* __restrict__ cursors,
                                                 int* __restrict__ perm,
                                                 int* __restrict__ srcs, int E)
{
    int e = blockIdx.x * 256 + threadIdx.x;
    if (e < E) {
        int pos = atomicAdd(&cursors[eidx[E + e]], 1);
        perm[pos] = e;
        srcs[pos] = eidx[e];
    }
}

// ---------------------------------------------------------------------------
// Radial-MLP TABLE build: T[j][c] = (silu(rbf(d_j)@W1+b1)@W2)[c] * env(d_j),
// d_j = j*TABLE_DT, j in [0, TABLE_N). Round-5 tiled-GEMM structure
// (64 samples/block, 256 threads, bank-conflict-free hT layout).
// ---------------------------------------------------------------------------
__global__ __launch_bounds__(256) void k_radtab(const float* __restrict__ w1,
                                                const float* __restrict__ b1,
                                                const float* __restrict__ w2,
                                                float* __restrict__ table)
{
    __shared__ float rbfT[64 * 64];   // [k][s]
    __shared__ float hT[128 * 64];    // [j][s]
    __shared__ float distS[64];
    __shared__ float envS[64];
    const int tid = threadIdx.x;
    const int base = blockIdx.x * 64;

    if (tid < 64) {
        float dist = (float)(base + tid) * TABLE_DT;
        distS[tid] = dist;
        float dd = dist * (1.0f / 6.0f);
        float env = 0.f;
        if (dd < 1.0f) {
            float d2 = dd * dd;
            float d5 = d2 * d2 * dd;
            env = 1.0f - 21.0f * d5 + 35.0f * d5 * dd - 15.0f * d5 * d2;
        }
        envS[tid] = env;
    }
    __syncthreads();
    const float step = 6.0f / 63.0f;
#pragma unroll
    for (int p = 0; p < 16; ++p) {
        int idx = p * 256 + tid;
        int k = idx >> 6, s2 = idx & 63;
        float diff = distS[s2] - step * (float)k;
        rbfT[idx] = __expf(-55.125f * diff * diff);
    }
    __syncthreads();

    // Phase B: h = silu(rbf @ W1 + b1) -> hT[j][s]
    {
        const int sg = tid & 15;        // 16 sample-groups of 4
        const int jg = tid >> 4;        // 16 j-groups of 8
        float hacc[4][8];
        float4 b0 = *(const float4*)&b1[jg * 8];
        float4 b4 = *(const float4*)&b1[jg * 8 + 4];
#pragma unroll
        for (int ee = 0; ee < 4; ++ee) {
            hacc[ee][0] = b0.x; hacc[ee][1] = b0.y; hacc[ee][2] = b0.z; hacc[ee][3] = b0.w;
            hacc[ee][4] = b4.x; hacc[ee][5] = b4.y; hacc[ee][6] = b4.z; hacc[ee][7] = b4.w;
        }
#pragma unroll 4
        for (int k = 0; k < 64; ++k) {
            float4 wa = *(const float4*)&w1[k * 128 + jg * 8];
            float4 wb = *(const float4*)&w1[k * 128 + jg * 8 + 4];
            float4 rb = *(const float4*)&rbfT[k * 64 + sg * 4];
            float r[4] = {rb.x, rb.y, rb.z, rb.w};
#pragma unroll
            for (int ee = 0; ee < 4; ++ee) {
                hacc[ee][0] += r[ee] * wa.x;
                hacc[ee][1] += r[ee] * wa.y;
                hacc[ee][2] += r[ee] * wa.z;
                hacc[ee][3] += r[ee] * wa.w;
                hacc[ee][4] += r[ee] * wb.x;
                hacc[ee][5] += r[ee] * wb.y;
                hacc[ee][6] += r[ee] * wb.z;
                hacc[ee][7] += r[ee] * wb.w;
            }
        }
#pragma unroll
        for (int jj = 0; jj < 8; ++jj) {
            float4 hv;
            hv.x = siluf(hacc[0][jj]);
            hv.y = siluf(hacc[1][jj]);
            hv.z = siluf(hacc[2][jj]);
            hv.w = siluf(hacc[3][jj]);
            *(float4*)&hT[(jg * 8 + jj) * 64 + sg * 4] = hv;
        }
    }
    __syncthreads();

    // Phase C: T = h @ W2 * env
    {
        const int sg = tid >> 4;
        const int tg = tid & 15;
        float acc[4][4];
#pragma unroll
        for (int ee = 0; ee < 4; ++ee)
#pragma unroll
            for (int tt = 0; tt < 4; ++tt) acc[ee][tt] = 0.f;
#pragma unroll 4
        for (int j = 0; j < 128; ++j) {
            float4 wv = *(const float4*)&w2[j * 64 + tg * 4];
            float4 hv = *(const float4*)&hT[j * 64 + sg * 4];
            float h[4] = {hv.x, hv.y, hv.z, hv.w};
#pragma unroll
            for (int ee = 0; ee < 4; ++ee) {
                acc[ee][0] += h[ee] * wv.x;
                acc[ee][1] += h[ee] * wv.y;
                acc[ee][2] += h[ee] * wv.z;
                acc[ee][3] += h[ee] * wv.w;
            }
        }
#pragma unroll
        for (int ee = 0; ee < 4; ++ee) {
            int s = base + sg * 4 + ee;
            if (s < TABLE_N) {
                float envv = envS[sg * 4 + ee];
                float4 o;
                o.x = acc[ee][0] * envv;
                o.y = acc[ee][1] * envv;
                o.z = acc[ee][2] * envv;
                o.w = acc[ee][3] * envv;
                *(float4*)&table[(size_t)s * 64 + tg * 4] = o;
            }
        }
    }
}

// ---------------------------------------------------------------------------
// Slim per-edge kernel, ONE THREAD PER EDGE in SORTED order:
// Wigner Q (20 live coeffs) -> Qe[i], plus dist -> distI[i]. No MLP.
// ---------------------------------------------------------------------------
__global__ __launch_bounds__(256) void k_edgeQ(const float* __restrict__ evec,
                                               const int* __restrict__ perm,
                                               const float* __restrict__ Jc,
                                               float* __restrict__ Qe,
                                               float* __restrict__ distI,
                                               int E)
{
    __shared__ float sJ[34];
    const int tid = threadIdx.x;
    if (tid < 34) sJ[tid] = Jc[tid];
    __syncthreads();

    const int i = blockIdx.x * 256 + tid;
    if (i >= E) return;
    const int e = perm[i];

    float vx = evec[(size_t)e * 3 + 0];
    float vy = evec[(size_t)e * 3 + 1];
    float vz = evec[(size_t)e * 3 + 2];
    float dist = sqrtf(vx * vx + vy * vy + vz * vz);
    float inv = 1.0f / fmaxf(dist, 1e-7f);
    float xn = fminf(fmaxf(vx * inv, -1.f), 1.f);
    float yn = fminf(fmaxf(vy * inv, -1.f), 1.f);
    float zn = fminf(fmaxf(vz * inv, -1.f), 1.f);
    float beta = acosf(fminf(fmaxf(yn, -1.f + 1e-7f), 1.f - 1e-7f));
    float alpha = atan2f(xn, zn);
    const float bA = -beta;
    const float cA = -alpha;

    distI[i] = dist;
    float* qo = Qe + (size_t)i * 20;

    // ---- Wigner l = 1 ----
    {
        const float* J1 = sJ;
        float cb[3], sb[3], cz[3], sz[3];
#pragma unroll
        for (int k = 0; k < 3; ++k) {
            __sincosf((float)(1 - k) * bA, &sb[k], &cb[k]);
            __sincosf((float)(k - 1) * cA, &sz[k], &cz[k]);
        }
        cb[1] = 0.f; cz[1] = 0.f;
        float A[2][3], Bc[3][2], W[2][2];
#pragma unroll
        for (int a = 0; a < 2; ++a) {
            int r = a * 2;
#pragma unroll
            for (int m = 0; m < 3; ++m)
                A[a][m] = J1[r * 3 + m] * cb[m] + J1[r * 3 + (2 - m)] * sb[2 - m];
        }
#pragma unroll
        for (int m = 0; m < 3; ++m)
#pragma unroll
            for (int b = 0; b < 2; ++b) {
                int c = b * 2;
                Bc[m][b] = J1[m * 3 + c] * cz[c] + J1[m * 3 + (2 - c)] * sz[c];
            }
#pragma unroll
        for (int a = 0; a < 2; ++a)
#pragma unroll
            for (int b = 0; b < 2; ++b) {
                float w = 0.f;
#pragma unroll
                for (int m = 0; m < 3; ++m) w += A[a][m] * Bc[m][b];
                W[a][b] = w;
            }
        float4 q;
        q.x = W[0][0] * W[0][0] + W[1][0] * W[1][0];
        q.y = W[0][0] * W[0][1] + W[1][0] * W[1][1];
        q.z = W[0][1] * W[0][0] + W[1][1] * W[1][0];
        q.w = W[0][1] * W[0][1] + W[1][1] * W[1][1];
        *(float4*)&qo[0] = q;
    }

    // ---- Wigner l = 2 ----
    {
        const float* J2 = sJ + 9;
        float cb[5], sb[5], cz[5], sz[5];
#pragma unroll
        for (int k = 0; k < 5; ++k) {
            __sincosf((float)(2 - k) * bA, &sb[k], &cb[k]);
            __sincosf((float)(k - 2) * cA, &sz[k], &cz[k]);
        }
        cb[2] = 0.f; cz[2] = 0.f;
        const int rmap[4] = {0, 1, 3, 4};
        float A[4][5], Bc[5][4], W[4][4];
#pragma unroll
        for (int a = 0; a < 4; ++a) {
            int r = rmap[a];
#pragma unroll
            for (int m = 0; m < 5; ++m)
                A[a][m] = J2[r * 5 + m] * cb[m] + J2[r * 5 + (4 - m)] * sb[4 - m];
        }
#pragma unroll
        for (int m = 0; m < 5; ++m)
#pragma unroll
            for (int b = 0; b < 4; ++b) {
                int c = rmap[b];
                Bc[m][b] = J2[m * 5 + c] * cz[c] + J2[m * 5 + (4 - c)] * sz[c];
            }
#pragma unroll
        for (int a = 0; a < 4; ++a)
#pragma unroll
            for (int b = 0; b < 4; ++b) {
                float w = 0.f;
#pragma unroll
                for (int m = 0; m < 5; ++m) w += A[a][m] * Bc[m][b];
                W[a][b] = w;
            }
#pragma unroll
        for (int a = 0; a < 4; ++a) {
            float4 q;
            q.x = W[0][a] * W[0][0] + W[1][a] * W[1][0] + W[2][a] * W[2][0] + W[3][a] * W[3][0];
            q.y = W[0][a] * W[0][1] + W[1][a] * W[1][1] + W[2][a] * W[2][1] + W[3][a] * W[3][1];
            q.z = W[0][a] * W[0][2] + W[1][a] * W[1][2] + W[2][a] * W[2][2] + W[3][a] * W[3][2];
            q.w = W[0][a] * W[0][3] + W[1][a] * W[1][3] + W[2][a] * W[2][3] + W[3][a] * W[3][3];
            *(float4*)&qo[4 + a * 4] = q;
        }
    }
}

// ---------------------------------------------------------------------------
// Per-dst-node gather: Qe/distI/srcs sequential (sorted layout); rad obtained
// by linear interpolation in the table; xm6[src] is the only random stream.
// Register accumulate + fused M2/RMS/gamma finalize.
// ---------------------------------------------------------------------------
__global__ __launch_bounds__(64) void k_gather_fin(const int* __restrict__ srcs,
                                                   const int* __restrict__ offsets,
                                                   const float* __restrict__ Qe,
                                                   const float* __restrict__ distI,
                                                   const float* __restrict__ table,
                                                   const float* __restrict__ xm6,
                                                   const float* __restrict__ m2,
                                                   const float* __restrict__ gam,
                                                   float* __restrict__ out)
{
    const int n = blockIdx.x;
    const int t = threadIdx.x;
    const int start = offsets[n];
    const int end = offsets[n + 1];

    float a1 = 0.f, a3 = 0.f, a4 = 0.f, a5 = 0.f, a7 = 0.f, a8 = 0.f;
    for (int i = start; i < end; ++i) {
        const int src = srcs[i];
        const float* q = Qe + (size_t)i * 20;
        float4 q0 = *(const float4*)&q[0];
        float4 q1 = *(const float4*)&q[4];
        float4 q2 = *(const float4*)&q[8];
        float4 q3 = *(const float4*)&q[12];
        float4 q4 = *(const float4*)&q[16];

        float u = fminf(distI[i] * TABLE_INV_DT, 8192.0f);
        int iu = (int)u;
        iu = (iu > 8191) ? 8191 : iu;
        float fr = u - (float)iu;
        const float* t0 = table + (size_t)iu * 64;
        float r0 = t0[t];
        float r1 = t0[64 + t];
        const float rad = r0 + fr * (r1 - r0);

        const float* xs = xm6 + (size_t)src * 384;
        float x1 = xs[0 * 64 + t];
        float x3 = xs[1 * 64 + t];
        float x4 = xs[2 * 64 + t];
        float x5 = xs[3 * 64 + t];
        float x7 = xs[4 * 64 + t];
        float x8 = xs[5 * 64 + t];
        a1 += rad * (q0.x * x1 + q0.y * x3);
        a3 += rad * (q0.z * x1 + q0.w * x3);
        a4 += rad * (q1.x * x4 + q1.y * x5 + q1.z * x7 + q1.w * x8);
        a5 += rad * (q2.x * x4 + q2.y * x5 + q2.z * x7 + q2.w * x8);
        a7 += rad * (q3.x * x4 + q3.y * x5 + q3.z * x7 + q3.w * x8);
        a8 += rad * (q4.x * x4 + q4.y * x5 + q4.z * x7 + q4.w * x8);
    }

    __shared__ float sa[6 * 64];
    sa[0 * 64 + t] = a1;
    sa[1 * 64 + t] = a3;
    sa[2 * 64 + t] = a4;
    sa[3 * 64 + t] = a5;
    sa[4 * 64 + t] = a7;
    sa[5 * 64 + t] = a8;
    __syncthreads();
    float v0 = 0.f, v1 = 0.f, v2 = 0.f, v3 = 0.f, v4 = 0.f, v5 = 0.f;
    for (int c = 0; c < 64; ++c) {
        float m = m2[c * 64 + t];
        v0 += sa[0 * 64 + c] * m;
        v1 += sa[1 * 64 + c] * m;
        v2 += sa[2 * 64 + c] * m;
        v3 += sa[3 * 64 + c] * m;
        v4 += sa[4 * 64 + c] * m;
        v5 += sa[5 * 64 + c] * m;
    }
    float ss = v0 * v0 + v1 * v1 + v2 * v2 + v3 * v3 + v4 * v4 + v5 * v5;
    float rms = sqrtf(ss * (1.0f / 9.0f) + 1e-7f);
    float sc = gam[t] / rms;
    float* op = out + (size_t)n * 576;
    op[0 * 64 + t] = 0.f;
    op[2 * 64 + t] = 0.f;
    op[6 * 64 + t] = 0.f;
    op[1 * 64 + t] = v0 * sc;
    op[3 * 64 + t] = v1 * sc;
    op[4 * 64 + t] = v2 * sc;
    op[5 * 64 + t] = v3 * sc;
    op[7 * 64 + t] = v4 * sc;
    op[8 * 64 + t] = v5 * sc;
}

// ---------------------------------------------------------------------------
// Legacy fallback path (small ws): LDS-phased k_rad + atomic scatter + finalize
// ---------------------------------------------------------------------------
__global__ __launch_bounds__(256, 4) void k_rad_lds(const float* __restrict__ evec,
                                                    const float* __restrict__ w1,
                                                    const float* __restrict__ b1,
                                                    const float* __restrict__ w2,
                                                    float* __restrict__ radg,
                                                    int E)
{
    __shared__ float rbfT[64 * 64];
    __shared__ float hT[32 * 64];
    __shared__ float distS[64];
    __shared__ float envS[64];
    const int tid = threadIdx.x;
    const int base = blockIdx.x * 64;

    if (tid < 64) {
        int e = base + tid;
        float dist = 0.f;
        if (e < E) {
            float vx = evec[(size_t)e * 3 + 0];
            float vy = evec[(size_t)e * 3 + 1];
            float vz = evec[(size_t)e * 3 + 2];
            dist = sqrtf(vx * vx + vy * vy + vz * vz);
        }
        distS[tid] = dist;
        float dd = dist * (1.0f / 6.0f);
        float env = 0.f;
        if (dd < 1.0f) {
            float d2 = dd * dd;
            float d5 = d2 * d2 * dd;
            env = 1.0f - 21.0f * d5 + 35.0f * d5 * dd - 15.0f * d5 * d2;
        }
        envS[tid] = env;
    }
    __syncthreads();

    const float step = 6.0f / 63.0f;
#pragma unroll
    for (int p = 0; p < 16; ++p) {
        int idx = p * 256 + tid;
        int k = idx >> 6, e2 = idx & 63;
        float diff = distS[e2] - step * (float)k;
        rbfT[idx] = __expf(-55.125f * diff * diff);
    }

    const int egB = tid & 15;
    const int jgB = tid >> 4;
    const int egC = tid >> 4;
    const int tgC = tid & 15;

    float acc[4][4];
#pragma unroll
    for (int ee = 0; ee < 4; ++ee)
#pragma unroll
        for (int cc = 0; cc < 4; ++cc) acc[ee][cc] = 0.f;

    for (int q = 0; q < 4; ++q) {
        float h00, h01, h10, h11, h20, h21, h30, h31;
        {
            const float2 bb = *(const float2*)&b1[q * 32 + jgB * 2];
            h00 = bb.x; h01 = bb.y; h10 = bb.x; h11 = bb.y;
            h20 = bb.x; h21 = bb.y; h30 = bb.x; h31 = bb.y;
            const float* w1p = w1 + q * 32 + jgB * 2;
#pragma unroll 4
            for (int k = 0; k < 64; ++k) {
                float2 wv = *(const float2*)&w1p[k * 128];
                float4 rb = *(const float4*)&rbfT[k * 64 + egB * 4];
                h00 += rb.x * wv.x; h01 += rb.x * wv.y;
                h10 += rb.y * wv.x; h11 += rb.y * wv.y;
                h20 += rb.z * wv.x; h21 += rb.z * wv.y;
                h30 += rb.w * wv.x; h31 += rb.w * wv.y;
            }
        }
        __syncthreads();
        {
            float4 v0, v1;
            v0.x = siluf(h00); v0.y = siluf(h10); v0.z = siluf(h20); v0.w = siluf(h30);
            v1.x = siluf(h01); v1.y = siluf(h11); v1.z = siluf(h21); v1.w = siluf(h31);
            *(float4*)&hT[(jgB * 2 + 0) * 64 + egB * 4] = v0;
            *(float4*)&hT[(jgB * 2 + 1) * 64 + egB * 4] = v1;
        }
        __syncthreads();

        const float* w2p = w2 + (size_t)(q * 32) * 64 + tgC * 4;
#pragma unroll 4
        for (int j2 = 0; j2 < 32; ++j2) {
            float4 wv = *(const float4*)&w2p[j2 * 64];
            float4 hv = *(const float4*)&hT[j2 * 64 + egC * 4];
            acc[0][0] += hv.x * wv.x; acc[0][1] += hv.x * wv.y;
            acc[0][2] += hv.x * wv.z; acc[0][3] += hv.x * wv.w;
            acc[1][0] += hv.y * wv.x; acc[1][1] += hv.y * wv.y;
            acc[1][2] += hv.y * wv.z; acc[1][3] += hv.y * wv.w;
            acc[2][0] += hv.z * wv.x; acc[2][1] += hv.z * wv.y;
            acc[2][2] += hv.z * wv.z; acc[2][3] += hv.z * wv.w;
            acc[3][0] += hv.w * wv.x; acc[3][1] += hv.w * wv.y;
            acc[3][2] += hv.w * wv.z; acc[3][3] += hv.w * wv.w;
        }
    }

#pragma unroll
    for (int ee = 0; ee < 4; ++ee) {
        int e = base + egC * 4 + ee;
        if (e < E) {
            float envv = envS[egC * 4 + ee];
            float4 o;
            o.x = acc[ee][0] * envv;
            o.y = acc[ee][1] * envv;
            o.z = acc[ee][2] * envv;
            o.w = acc[ee][3] * envv;
            *(float4*)&radg[(size_t)e * 64 + tgC * 4] = o;
        }
    }
}

__device__ __forceinline__ float wig_entry(int l, int i, int j, float bA, float cA,
                                           const float* __restrict__ J, int n)
{
    if (i == l) return 0.f;
    const int j2 = 2 * l - j;
    float Pij = 0.f, Pij2 = 0.f;
    for (int k = 0; k < n; ++k) {
        float sbk, cbk;
        __sincosf((float)(l - k) * bA, &sbk, &cbk);
        if (k == l) cbk = 0.f;
        float zj  = cbk * J[k * n + j]  + sbk * J[(2 * l - k) * n + j];
        float zj2 = cbk * J[k * n + j2] + sbk * J[(2 * l - k) * n + j2];
        Pij  += J[i * n + k] * zj;
        Pij2 += J[i * n + k] * zj2;
    }
    float s_, c_;
    __sincosf((float)(l - j) * cA, &s_, &c_);
    float czj = (j == l) ? 0.f : c_;
    float szj = -s_;
    return Pij * czj + Pij2 * szj;
}

__global__ __launch_bounds__(64) void k_edge2(const float* __restrict__ evec,
                                              const int* __restrict__ eidx,
                                              const float* __restrict__ radg,
                                              const float* __restrict__ Jc,
                                              const float* __restrict__ xm6,
                                              float* __restrict__ acc, int E)
{
    const int e = blockIdx.x;
    const int t = threadIdx.x;
    __shared__ float s_W1[9], s_W2[25], s_Q1[9], s_Q2[25];

    float vx = evec[(size_t)e * 3 + 0];
    float vy = evec[(size_t)e * 3 + 1];
    float vz = evec[(size_t)e * 3 + 2];
    float dist = sqrtf(vx * vx + vy * vy + vz * vz);
    float inv = 1.0f / fmaxf(dist, 1e-7f);
    float xn = fminf(fmaxf(vx * inv, -1.f), 1.f);
    float yn = fminf(fmaxf(vy * inv, -1.f), 1.f);
    float zn = fminf(fmaxf(vz * inv, -1.f), 1.f);
    float beta = acosf(fminf(fmaxf(yn, -1.f + 1e-7f), 1.f - 1e-7f));
    float alpha = atan2f(xn, zn);
    float bA = -beta;
    float cA = -alpha;

    if (t < 25) {
        s_W2[t] = wig_entry(2, t / 5, t % 5, bA, cA, Jc + 9, 5);
    } else if (t >= 32 && t < 41) {
        int u = t - 32;
        s_W1[u] = wig_entry(1, u / 3, u % 3, bA, cA, Jc, 3);
    }
    __syncthreads();

    if (t < 25) {
        int i = t / 5, j = t % 5;
        float qv = 0.f;
#pragma unroll
        for (int k = 0; k < 5; ++k) qv += s_W2[k * 5 + i] * s_W2[k * 5 + j];
        s_Q2[t] = qv;
    } else if (t >= 32 && t < 41) {
        int u = t - 32;
        int i = u / 3, j = u % 3;
        float qv = 0.f;
#pragma unroll
        for (int k = 0; k < 3; ++k) qv += s_W1[k * 3 + i] * s_W1[k * 3 + j];
        s_Q1[u] = qv;
    }
    __syncthreads();

    const float rad = radg[(size_t)e * 64 + t];
    const int src = eidx[e];
    const int dst = eidx[E + e];
    const float* xs = xm6 + (size_t)src * 384;
    float x1 = xs[0 * 64 + t];
    float x3 = xs[1 * 64 + t];
    float x4 = xs[2 * 64 + t];
    float x5 = xs[3 * 64 + t];
    float x7 = xs[4 * 64 + t];
    float x8 = xs[5 * 64 + t];

    float m1v = rad * (s_Q1[0] * x1 + s_Q1[2] * x3);
    float m3v = rad * (s_Q1[6] * x1 + s_Q1[8] * x3);
    float m4v = rad * (s_Q2[0]  * x4 + s_Q2[1]  * x5 + s_Q2[3]  * x7 + s_Q2[4]  * x8);
    float m5v = rad * (s_Q2[5]  * x4 + s_Q2[6]  * x5 + s_Q2[8]  * x7 + s_Q2[9]  * x8);
    float m7v = rad * (s_Q2[15] * x4 + s_Q2[16] * x5 + s_Q2[18] * x7 + s_Q2[19] * x8);
    float m8v = rad * (s_Q2[20] * x4 + s_Q2[21] * x5 + s_Q2[23] * x7 + s_Q2[24] * x8);

    float* ad = acc + (size_t)dst * 576;
    atomicAdd(ad + 1 * 64 + t, m1v);
    atomicAdd(ad + 3 * 64 + t, m3v);
    atomicAdd(ad + 4 * 64 + t, m4v);
    atomicAdd(ad + 5 * 64 + t, m5v);
    atomicAdd(ad + 7 * 64 + t, m7v);
    atomicAdd(ad + 8 * 64 + t, m8v);
}

__global__ __launch_bounds__(64) void k_fin(const float* __restrict__ m2,
                                            const float* __restrict__ gam,
                                            float* __restrict__ out)
{
    const int n = blockIdx.x;
    const int t = threadIdx.x;
    __shared__ float sa[6 * 64];
    float* op = out + (size_t)n * 576;
    sa[0 * 64 + t] = op[1 * 64 + t];
    sa[1 * 64 + t] = op[3 * 64 + t];
    sa[2 * 64 + t] = op[4 * 64 + t];
    sa[3 * 64 + t] = op[5 * 64 + t];
    sa[4 * 64 + t] = op[7 * 64 + t];
    sa[5 * 64 + t] = op[8 * 64 + t];
    __syncthreads();
    float v0 = 0.f, v1 = 0.f, v2 = 0.f, v3 = 0.f, v4 = 0.f, v5 = 0.f;
    for (int c = 0; c < 64; ++c) {
        float m = m2[c * 64 + t];
        v0 += sa[0 * 64 + c] * m;
        v1 += sa[1 * 64 + c] * m;
        v2 += sa[2 * 64 + c] * m;
        v3 += sa[3 * 64 + c] * m;
        v4 += sa[4 * 64 + c] * m;
        v5 += sa[5 * 64 + c] * m;
    }
    float ss = v0 * v0 + v1 * v1 + v2 * v2 + v3 * v3 + v4 * v4 + v5 * v5;
    float rms = sqrtf(ss * (1.0f / 9.0f) + 1e-7f);
    float sc = gam[t] / rms;
    op[0 * 64 + t] = 0.f;
    op[2 * 64 + t] = 0.f;
    op[6 * 64 + t] = 0.f;
    op[1 * 64 + t] = v0 * sc;
    op[3 * 64 + t] = v1 * sc;
    op[4 * 64 + t] = v2 * sc;
    op[5 * 64 + t] = v3 * sc;
    op[7 * 64 + t] = v4 * sc;
    op[8 * 64 + t] = v5 * sc;
}

static inline size_t align256(size_t x) { return (x + 255) & ~(size_t)255; }

extern "C" void kernel_launch(void* const* d_in, const int* in_sizes, int n_in,
                              void* d_out, int out_size, void* d_ws, size_t ws_size,
                              hipStream_t stream)
{
    const float* nf  = (const float*)d_in[0];
    const float* ev  = (const float*)d_in[1];
    const int*   ei  = (const int*)d_in[2];
    const float* w1  = (const float*)d_in[3];
    const float* b1  = (const float*)d_in[4];
    const float* w2  = (const float*)d_in[5];
    const float* m1  = (const float*)d_in[6];
    const float* m2  = (const float*)d_in[7];
    const float* gam = (const float*)d_in[8];

    const int N = in_sizes[0] / (SPHN * CHN);
    const int E = in_sizes[1] / 3;

    float* out = (float*)d_out;
    char* base = (char*)d_ws;
    size_t off = 0;
    float* Jc = (float*)(base + off);            off += align256(34 * sizeof(float));
    float* xm6 = (float*)(base + off);           off += align256((size_t)N * 384 * sizeof(float));
    float* radg = (float*)(base + off);          off += align256((size_t)E * 64 * sizeof(float));
    size_t need_old = off;                       // through radg
    float* Qe = (float*)(base + off);            off += align256((size_t)E * 20 * sizeof(float));
    int* counts = (int*)(base + off);            off += align256((size_t)N * sizeof(int));
    int* offsets = (int*)(base + off);           off += align256((size_t)(N + 1) * sizeof(int));
    int* cursors = (int*)(base + off);           off += align256((size_t)N * sizeof(int));
    int* perm = (int*)(base + off);              off += align256((size_t)E * sizeof(int));
    int* srcs = (int*)(base + off);              off += align256((size_t)E * sizeof(int));
    size_t need_new = off;

    // New path: table + distI alias the (unused) radg slot.
    // table = TABLE_N*64 floats = 524,352 floats; distI = E floats; slot = E*64.
    float* table = radg;
    float* distI = radg + (size_t)TABLE_N * 64;  // byte off 2,097,408 (256-aligned)

    if (ws_size >= need_new && (size_t)TABLE_N * 64 + (size_t)E <= (size_t)E * 64) {
        hipLaunchKernelGGL(k_setup, dim3((N + 255) / 256), dim3(256), 0, stream,
                           Jc, counts, N);
        hipLaunchKernelGGL(k_hist, dim3((E + 255) / 256), dim3(256), 0, stream,
                           ei, counts, E);
        hipLaunchKernelGGL(k_scan, dim3(1), dim3(1024), 0, stream,
                           counts, offsets, cursors, N);
        hipLaunchKernelGGL(k_scatter, dim3((E + 255) / 256), dim3(256), 0, stream,
                           ei, cursors, perm, srcs, E);
        hipLaunchKernelGGL(k_xm, dim3((N + 3) / 4), dim3(256), 0, stream,
                           nf, m1, xm6, N);
        hipLaunchKernelGGL(k_radtab, dim3((TABLE_N + 63) / 64), dim3(256), 0, stream,
                           w1, b1, w2, table);
        hipLaunchKernelGGL(k_edgeQ, dim3((E + 255) / 256), dim3(256), 0, stream,
                           ev, perm, Jc, Qe, distI, E);
        hipLaunchKernelGGL(k_gather_fin, dim3(N), dim3(64), 0, stream,
                           srcs, offsets, Qe, distI, table, xm6, m2, gam, out);
    } else if (ws_size >= need_old) {
        hipLaunchKernelGGL(k_setup, dim3(1), dim3(256), 0, stream,
                           Jc, (int*)nullptr, 0);
        hipLaunchKernelGGL(k_xm, dim3((N + 3) / 4), dim3(256), 0, stream,
                           nf, m1, xm6, N);
        hipMemsetAsync(d_out, 0, (size_t)out_size * sizeof(float), stream);
        hipLaunchKernelGGL(k_rad_lds, dim3((E + 63) / 64), dim3(256), 0, stream,
                           ev, w1, b1, w2, radg, E);
        hipLaunchKernelGGL(k_edge2, dim3(E), dim3(64), 0, stream,
                           ev, ei, radg, Jc, xm6, out, E);
        hipLaunchKernelGGL(k_fin, dim3(N), dim3(64), 0, stream, m2, gam, out);
    }
}